// Round 7
// baseline (168.857 us; speedup 1.0000x reference)
//
#include <hip/hip_runtime.h>
#include <math.h>

// KDE log-density: out[i] = log(1e-8 + (1/N) * sum_j exp(t1 - 50*||xe_i - xb_j||^2))
// N = 16384, D = 16, fp32 in/out.
//
// Round 7: G=4 register-cached-A (R6) minus the spill. R6 carried 4 x 16
// MFMA C-operand regs of per-row bias (perv) -> allocator spilled to scratch
// (WRITE_SIZE 57 MB, kde_main 65 us). Now MFMA runs with C = 0 and the
// screen uses a wave-uniform per-m-tile bound maxpe_g (shfl-reduced once in
// the prologue): any(mx_d > thrv - maxpe_g) is conservative (only false
// positives). The rare hit path reloads pe[row] from L2 and computes the
// exact term. ~60 VGPRs -> no spill, 8 waves/SIMD.
//
// Numerics: inputs pre-scaled by sqrt(100*log2e) before bf16 cast, so
// d = 144.2695*dot; term survives iff d + pe[row] + pb[col] > THR=-135
// (dropped terms < 2^-135 shift the output < 1e-37; bf16 rounding safe since
// min pairwise sqdist >> 0.14). Hit path: atomicAdd S, then monotone
// atomicMin of log(1e-8+S_new/N) raw bits into out (all negative =>
// float-max == uint-min); kde_pre pre-writes out = log(1e-8).
// No LDS, no barriers, no device-scope fences (R4 lesson).

#define KDE_N 16384
#define KDE_D 16
#define G 4                    // A m-tiles register-cached per wave
#define THR (-135.0f)          // log2-domain underflow screen

typedef __attribute__((ext_vector_type(8)))  short   short8;
typedef __attribute__((ext_vector_type(16))) float   float16_t;

__device__ __forceinline__ unsigned short f32_to_bf16_rne(float f) {
    unsigned int u = __float_as_uint(f);
    unsigned int r = (u + 0x7FFFu + ((u >> 16) & 1u)) >> 16;
    return (unsigned short)r;
}

// ---- prologue: pe / (THR - pb), scaled bf16 casts, zero S, default out ----
__global__ void kde_pre(const float* __restrict__ xe, const float* __restrict__ xb,
                        float* __restrict__ S, float* __restrict__ pe,
                        float* __restrict__ pbthr, unsigned short* __restrict__ xe16,
                        unsigned short* __restrict__ xb16, float* __restrict__ out)
{
    const int t = blockIdx.x * blockDim.x + threadIdx.x;   // 0..32767
    const int row = t & (KDE_N - 1);
    const bool isB = t >= KDE_N;
    const float* src = (isB ? xb : xe) + (size_t)row * KDE_D;
    const float4* s4 = (const float4*)src;
    const float SQSC = 12.011224664550577f;   // sqrt(100*log2e)
    float q = 0.f;
    unsigned int w[8];
    #pragma unroll
    for (int k = 0; k < 4; ++k) {
        float4 v = s4[k];
        q += v.x*v.x + v.y*v.y + v.z*v.z + v.w*v.w;
        w[2*k+0] = (unsigned int)f32_to_bf16_rne(v.x * SQSC)
                 | ((unsigned int)f32_to_bf16_rne(v.y * SQSC) << 16);
        w[2*k+1] = (unsigned int)f32_to_bf16_rne(v.z * SQSC)
                 | ((unsigned int)f32_to_bf16_rne(v.w * SQSC) << 16);
    }
    unsigned short* dst = (isB ? xb16 : xe16) + (size_t)row * KDE_D;
    uint4* d4 = (uint4*)dst;
    d4[0] = make_uint4(w[0], w[1], w[2], w[3]);
    d4[1] = make_uint4(w[4], w[5], w[6], w[7]);
    const float T1L2E  = -17.8920067984f;       // log2e * t1
    const float C72    = 72.134752044447963f;   // 50 * log2e
    const float LOG1EM8 = -18.420680743952367f; // log(1e-8)
    if (!isB) { pe[row] = T1L2E - C72 * q; S[row] = 0.f; out[row] = LOG1EM8; }
    else      { pbthr[row] = THR + C72 * q; }   // THR - pb,  pb = -C72*b2
}

// ---- main: 4 A-tiles in regs, C=0, wave-uniform pe bound; rare exp path ----
__global__ __launch_bounds__(256, 4) void kde_main(
    const unsigned short* __restrict__ xe16, const unsigned short* __restrict__ xb16,
    const float* __restrict__ pe, const float* __restrict__ pbthr,
    float* __restrict__ S, float* __restrict__ out)
{
    const int lane = threadIdx.x & 63;
    const int wave = threadIdx.x >> 6;
    const int col  = lane & 31;   // A row / B col / C col
    const int half = lane >> 5;   // k-half for A/B frags; row-group/4 for C

    const int m0     = blockIdx.x * (32 * G);          // 128 rows per block
    const int jslice = blockIdx.y * 4 + wave;          // 0..63
    const int j0     = jslice * 256;                   // 8 B-tiles per wave

    // A fragments + wave-uniform max(pe) per m-tile
    short8 af[G];
    float  maxpe[G];
    #pragma unroll
    for (int g = 0; g < G; ++g) {
        const int mg = m0 + g * 32;
        af[g] = *(const short8*)(xe16 + (size_t)(mg + col) * KDE_D + half * 8);
        float p = pe[mg + col];                        // 32 distinct rows/half
        #pragma unroll
        for (int m = 1; m < 32; m <<= 1)
            p = fmaxf(p, __shfl_xor(p, m, 32));
        maxpe[g] = p;                                  // uniform across wave
    }

    const float INVN = 1.0f / (float)KDE_N;
    const float16_t z = {0.f,0.f,0.f,0.f,0.f,0.f,0.f,0.f,
                         0.f,0.f,0.f,0.f,0.f,0.f,0.f,0.f};

    auto screen = [&](const float16_t& d, float thrv, float mpe, int mg) {
        float m1 = fmaxf(fmaxf(d[0],  d[1]),  d[2]);
        float m2 = fmaxf(fmaxf(d[3],  d[4]),  d[5]);
        float m3 = fmaxf(fmaxf(d[6],  d[7]),  d[8]);
        float m4 = fmaxf(fmaxf(d[9],  d[10]), d[11]);
        float m5 = fmaxf(fmaxf(d[12], d[13]), d[14]);
        float x  = fmaxf(fmaxf(m1, m2), m3);
        float y  = fmaxf(fmaxf(m4, m5), d[15]);
        float mx = fmaxf(x, y);
        if (__any(mx > thrv - mpe)) {      // conservative: mpe >= pe[row]
            const float pbv = THR - thrv;  // = pb[col]
            #pragma unroll
            for (int r = 0; r < 16; ++r) {
                const int row = mg + (r & 3) + 8 * (r >> 2) + 4 * half;
                float e = exp2f(d[r] + pe[row] + pbv);
                if (e != 0.f) {
                    float old  = atomicAdd(&S[row], e);
                    float cand = logf(1e-8f + (old + e) * INVN);
                    // all cands negative: float-max == uint-min on raw bits
                    atomicMin((unsigned int*)&out[row], __float_as_uint(cand));
                }
            }
        }
    };

    const unsigned short* bp = xb16 + (size_t)(j0 + col) * KDE_D + half * 8;
    const float*          tp = pbthr + (j0 + col);
    short8 bf   = *(const short8*)bp;
    float  thrv = *tp;

    #pragma unroll
    for (int t = 0; t < 7; ++t) {
        bp += 32 * KDE_D;  tp += 32;
        const short8 bf_n  = *(const short8*)bp;   // prefetch next B-tile
        const float  thr_n = *tp;
        #pragma unroll
        for (int g = 0; g < G; ++g) {
            float16_t d = __builtin_amdgcn_mfma_f32_32x32x16_bf16(af[g], bf, z, 0, 0, 0);
            screen(d, thrv, maxpe[g], m0 + g * 32);
        }
        bf = bf_n; thrv = thr_n;
    }
    {   // peeled last B-tile (no prefetch)
        #pragma unroll
        for (int g = 0; g < G; ++g) {
            float16_t d = __builtin_amdgcn_mfma_f32_32x32x16_bf16(af[g], bf, z, 0, 0, 0);
            screen(d, thrv, maxpe[g], m0 + g * 32);
        }
    }
}

extern "C" void kernel_launch(void* const* d_in, const int* in_sizes, int n_in,
                              void* d_out, int out_size, void* d_ws, size_t ws_size,
                              hipStream_t stream)
{
    const float* xe = (const float*)d_in[0];  // x_eval [16384,16] fp32
    const float* xb = (const float*)d_in[1];  // x_base [16384,16] fp32
    float* out = (float*)d_out;

    // ws layout: S[16384] | pe[16384] | pbthr[16384] | xe16 | xb16
    float* S     = (float*)d_ws;
    float* pe    = S + KDE_N;
    float* pbthr = pe + KDE_N;
    unsigned short* xe16 = (unsigned short*)(pbthr + KDE_N);
    unsigned short* xb16 = xe16 + (size_t)KDE_N * KDE_D;

    kde_pre<<<(2 * KDE_N) / 256, 256, 0, stream>>>(xe, xb, S, pe, pbthr, xe16, xb16, out);
    dim3 grid(KDE_N / (32 * G), 16);   // (128, 16) = 2048 blocks
    kde_main<<<grid, 256, 0, stream>>>(xe16, xb16, pe, pbthr, S, out);
}

// Round 8
// 95.536 us; speedup vs baseline: 1.7675x; 1.7675x over previous
//
#include <hip/hip_runtime.h>
#include <math.h>

// KDE log-density: out[i] = log(1e-8 + (1/N) * sum_j exp(t1 - 50*||xe_i - xb_j||^2))
// N = 16384, D = 16, fp32 in/out.
//
// Round 8 = Round 5 core (the 69.3 us configuration) + depth-3 B prefetch.
//   R6 lesson: G=4 per-row pe in C-operands -> 64 live VGPRs -> scratch spill
//     (WRITE_SIZE 57 MB). R7 lesson: replacing per-row pe with a wave-uniform
//     max bound destroys screen selectivity (pe spans ~700 in log2 units
//     across 32 rows; false-positive rate ~1 -> VALUBusy 64%, 123 us).
//   => G=1 with exact per-row pe riding the single MFMA C-operand is the
//     right point. R5's residual was latency (issue model 4.8 us vs ~18 us
//     actual, 1-deep prefetch = ~45 cy lookahead vs ~100-200 cy L1/L2)
//     -> explicit 3-deep rotating prefetch ring, VGPR ~52, 8 waves/SIMD.
//
// Numerics: inputs pre-scaled by sqrt(100*log2e) before bf16 cast, so
// d = 144.2695*dot + pe (pe in C operand); tile screened unless some
// d > THR - pb[col] (dropped terms < 2^-135 shift the output < 1e-37; bf16
// rounding safe since min pairwise sqdist >> 0.14). Rare hit path: atomicAdd
// into S, then monotone atomicMin of log(1e-8 + S_new/N) raw bits into out
// (all values negative => float-max == uint-min); kde_pre pre-writes
// out = log(1e-8), correct whenever S stays 0 (~every row).
// No LDS, no barriers, no device-scope fences (R4 lesson: a serialized
// agent-scope acq/rel ticket cost ~150 us).

#define KDE_N 16384
#define KDE_D 16
#define MT 32                  // rows per wave m-tile
#define MWAVES 4               // waves per block
#define MB (MT * MWAVES)       // 128 eval rows per block
#define JSPLIT 16
#define JTILES (KDE_N / 32 / JSPLIT)   // 32 j-tiles per wave
#define PF 3                   // B prefetch depth
#define THR (-135.0f)          // log2-domain underflow screen

typedef __attribute__((ext_vector_type(8)))  short   short8;
typedef __attribute__((ext_vector_type(16))) float   float16_t;

__device__ __forceinline__ unsigned short f32_to_bf16_rne(float f) {
    unsigned int u = __float_as_uint(f);
    unsigned int r = (u + 0x7FFFu + ((u >> 16) & 1u)) >> 16;
    return (unsigned short)r;
}

// ---- prologue: pe / (THR - pb), scaled bf16 casts, zero S, default out ----
__global__ void kde_pre(const float* __restrict__ xe, const float* __restrict__ xb,
                        float* __restrict__ S, float* __restrict__ pe,
                        float* __restrict__ pbthr, unsigned short* __restrict__ xe16,
                        unsigned short* __restrict__ xb16, float* __restrict__ out)
{
    const int t = blockIdx.x * blockDim.x + threadIdx.x;   // 0..32767
    const int row = t & (KDE_N - 1);
    const bool isB = t >= KDE_N;
    const float* src = (isB ? xb : xe) + (size_t)row * KDE_D;
    const float4* s4 = (const float4*)src;
    const float SQSC = 12.011224664550577f;   // sqrt(100*log2e)
    float q = 0.f;
    unsigned int w[8];
    #pragma unroll
    for (int k = 0; k < 4; ++k) {
        float4 v = s4[k];
        q += v.x*v.x + v.y*v.y + v.z*v.z + v.w*v.w;
        w[2*k+0] = (unsigned int)f32_to_bf16_rne(v.x * SQSC)
                 | ((unsigned int)f32_to_bf16_rne(v.y * SQSC) << 16);
        w[2*k+1] = (unsigned int)f32_to_bf16_rne(v.z * SQSC)
                 | ((unsigned int)f32_to_bf16_rne(v.w * SQSC) << 16);
    }
    unsigned short* dst = (isB ? xb16 : xe16) + (size_t)row * KDE_D;
    uint4* d4 = (uint4*)dst;
    d4[0] = make_uint4(w[0], w[1], w[2], w[3]);
    d4[1] = make_uint4(w[4], w[5], w[6], w[7]);
    const float T1L2E  = -17.8920067984f;       // log2e * t1
    const float C72    = 72.134752044447963f;   // 50 * log2e
    const float LOG1EM8 = -18.420680743952367f; // log(1e-8)
    if (!isB) { pe[row] = T1L2E - C72 * q; S[row] = 0.f; out[row] = LOG1EM8; }
    else      { pbthr[row] = THR + C72 * q; }   // THR - pb,  pb = -C72*b2
}

// ---- main: MFMA (C = per-row pe) + screen; 3-deep B prefetch ring ----
__global__ __launch_bounds__(256, 8) void kde_main(
    const unsigned short* __restrict__ xe16, const unsigned short* __restrict__ xb16,
    const float* __restrict__ pe, const float* __restrict__ pbthr,
    float* __restrict__ S, float* __restrict__ out)
{
    const int lane = threadIdx.x & 63;
    const int wave = threadIdx.x >> 6;
    const int m0   = blockIdx.x * MB + wave * MT;
    const int jt0  = blockIdx.y * JTILES;

    const int col  = lane & 31;   // A row / B col / C col
    const int half = lane >> 5;   // k-half for A/B frags; row-group for C

    // A fragment, loaded once (K=16 == D)
    const short8 af = *(const short8*)(xe16 + (size_t)(m0 + col) * KDE_D + half * 8);

    // C operand = exact per-row pe: row = (r&3)+8*(r>>2)+4*half
    float16_t perv;
    #pragma unroll
    for (int r = 0; r < 16; ++r)
        perv[r] = pe[m0 + (r & 3) + 8 * (r >> 2) + 4 * half];

    const float INVN = 1.0f / (float)KDE_N;

    auto screen = [&](const float16_t& d, float thrv) {
        float m1 = fmaxf(fmaxf(d[0],  d[1]),  d[2]);
        float m2 = fmaxf(fmaxf(d[3],  d[4]),  d[5]);
        float m3 = fmaxf(fmaxf(d[6],  d[7]),  d[8]);
        float m4 = fmaxf(fmaxf(d[9],  d[10]), d[11]);
        float m5 = fmaxf(fmaxf(d[12], d[13]), d[14]);
        float x  = fmaxf(fmaxf(m1, m2), m3);
        float y  = fmaxf(fmaxf(m4, m5), d[15]);
        float mx = fmaxf(x, y);
        if (__any(mx > thrv)) {
            // rare: some term may exceed 2^-135
            const float pbv = THR - thrv;   // = pb[col]
            #pragma unroll
            for (int r = 0; r < 16; ++r) {
                float e = exp2f(d[r] + pbv);
                if (e != 0.f) {
                    const int row = m0 + (r & 3) + 8 * (r >> 2) + 4 * half;
                    float old  = atomicAdd(&S[row], e);
                    float cand = logf(1e-8f + (old + e) * INVN);
                    // all cands negative: float-max == uint-min on raw bits
                    atomicMin((unsigned int*)&out[row], __float_as_uint(cand));
                }
            }
        }
    };

    const unsigned short* bbase = xb16 + (size_t)(jt0 * 32 + col) * KDE_D + half * 8;
    const float*          tbase = pbthr + (jt0 * 32 + col);

    // 3-deep rotating prefetch ring (WAR on ring slots caps loads in flight)
    short8 bfq[PF];
    float  thrq[PF];
    #pragma unroll
    for (int p = 0; p < PF; ++p) {
        bfq[p]  = *(const short8*)(bbase + (size_t)p * 32 * KDE_D);
        thrq[p] = tbase[p * 32];
    }

    #pragma unroll
    for (int t = 0; t < JTILES; ++t) {
        const short8 bf   = bfq[t % PF];
        const float  thrv = thrq[t % PF];
        if (t + PF < JTILES) {
            bfq[t % PF]  = *(const short8*)(bbase + (size_t)(t + PF) * 32 * KDE_D);
            thrq[t % PF] = tbase[(t + PF) * 32];
        }
        float16_t d = __builtin_amdgcn_mfma_f32_32x32x16_bf16(af, bf, perv, 0, 0, 0);
        screen(d, thrv);
    }
}

extern "C" void kernel_launch(void* const* d_in, const int* in_sizes, int n_in,
                              void* d_out, int out_size, void* d_ws, size_t ws_size,
                              hipStream_t stream)
{
    const float* xe = (const float*)d_in[0];  // x_eval [16384,16] fp32
    const float* xb = (const float*)d_in[1];  // x_base [16384,16] fp32
    float* out = (float*)d_out;

    // ws layout: S[16384] | pe[16384] | pbthr[16384] | xe16 | xb16
    float* S     = (float*)d_ws;
    float* pe    = S + KDE_N;
    float* pbthr = pe + KDE_N;
    unsigned short* xe16 = (unsigned short*)(pbthr + KDE_N);
    unsigned short* xb16 = xe16 + (size_t)KDE_N * KDE_D;

    kde_pre<<<(2 * KDE_N) / 256, 256, 0, stream>>>(xe, xb, S, pe, pbthr, xe16, xb16, out);
    dim3 grid(KDE_N / MB, JSPLIT);   // (128, 16) = 2048 blocks
    kde_main<<<grid, MWAVES * 64, 0, stream>>>(xe16, xb16, pe, pbthr, S, out);
}